// Round 4
// baseline (181.836 us; speedup 1.0000x reference)
//
#include <hip/hip_runtime.h>
#include <hip/hip_cooperative_groups.h>

namespace cg = cooperative_groups;

#define BATCH     32768
#define IN_DIM    256
#define N_NEURONS 128
#define DEG1      8                    // MAX_DEGREE+1
#define FEAT      (IN_DIM * DEG1)      // 2048
#define F4        (FEAT / 4)           // 512 float4 columns
#define XR4       (IN_DIM / 4)         // 64 float4 per x row
#define RPW       16                   // rows/wave, two-kernel path
#define RPW_F     8                    // rows/wave, fused path (low reg pressure)
#define NBLK_F    1024                 // 1024 * 4 waves * 8 rows = 32768

// ===========================================================================
// Two-kernel fallback path (round-2 proven: pass, absmax 0.0625)
// ===========================================================================
__global__ __launch_bounds__(256) void reduce_coeffs(const float* __restrict__ coeffs,
                                                     float* __restrict__ csum) {
    __shared__ float4 part[256];
    const int t = threadIdx.x;
    const int c = t & 7;
    const int g = t >> 3;
    const int col4 = blockIdx.x * 8 + c;

    const float4* p = (const float4*)coeffs + (size_t)(g * 4) * F4 + col4;
    float4 s = make_float4(0.f, 0.f, 0.f, 0.f);
#pragma unroll
    for (int n = 0; n < 4; ++n) {
        float4 v = p[(size_t)n * F4];
        s.x += v.x; s.y += v.y; s.z += v.z; s.w += v.w;
    }
    part[t] = s;
    __syncthreads();
#pragma unroll
    for (int stride = 128; stride >= 8; stride >>= 1) {
        if (t < stride) {
            float4 o = part[t + stride];
            float4 m = part[t];
            m.x += o.x; m.y += o.y; m.z += o.z; m.w += o.w;
            part[t] = m;
        }
        __syncthreads();
    }
    if (t < 8) ((float4*)csum)[blockIdx.x * 8 + t] = part[t];
}

__global__ __launch_bounds__(256) void kan_fwd(const float* __restrict__ x,
                                               const float* __restrict__ csum,
                                               float* __restrict__ out) {
    const int lane = threadIdx.x & 63;
    const int wave = threadIdx.x >> 6;
    const int row0 = (blockIdx.x * 4 + wave) * RPW;

    float c[4][8];
    const float4* c4 = (const float4*)csum + (size_t)lane * 8;
#pragma unroll
    for (int j = 0; j < 4; ++j) {
        float4 a = c4[j * 2];
        float4 b = c4[j * 2 + 1];
        c[j][0] = a.x; c[j][1] = a.y; c[j][2] = a.z; c[j][3] = a.w;
        c[j][4] = b.x; c[j][5] = b.y; c[j][6] = b.z; c[j][7] = b.w;
    }

    float acc[RPW];
    const float4* xr = (const float4*)x + (size_t)row0 * XR4 + lane;
#pragma unroll
    for (int r = 0; r < RPW; ++r) {
        float4 xv = xr[(size_t)r * XR4];
        float xs[4] = {xv.x, xv.y, xv.z, xv.w};
        float a = 0.f;
#pragma unroll
        for (int j = 0; j < 4; ++j) {
            const float xx = xs[j];
            const float two_x = xx + xx;
            a = fmaf(c[j][1], xx, a + c[j][0]);
            float tp = 1.f, tc = xx;
#pragma unroll
            for (int d = 2; d < 8; ++d) {
                float tn = fmaf(two_x, tc, -tp);
                a = fmaf(c[j][d], tn, a);
                tp = tc; tc = tn;
            }
        }
        acc[r] = a;
    }

#pragma unroll
    for (int rq = 0; rq < RPW / 4; ++rq) {
        float s[4];
#pragma unroll
        for (int k = 0; k < 4; ++k) {
            float a = acc[rq * 4 + k];
#pragma unroll
            for (int off = 32; off > 0; off >>= 1) a += __shfl_down(a, off, 64);
            s[k] = a;
        }
        if (lane == 0)
            ((float4*)out)[row0 / 4 + rq] = make_float4(s[0], s[1], s[2], s[3]);
    }
}

// ===========================================================================
// Fused cooperative kernel (RPW_F=8 keeps peak ~110 VGPRs -> 4 blocks/CU,
// capacity 1024 = grid, comfortable co-residency margin).
// ===========================================================================
__global__ __launch_bounds__(256) void kan_fused(const float* __restrict__ x,
                                                 const float* __restrict__ coeffs,
                                                 float* __restrict__ out,
                                                 float* __restrict__ csum) {
    cg::grid_group grid = cg::this_grid();

    const int lane = threadIdx.x & 63;
    const int wave = threadIdx.x >> 6;
    const int row0 = (blockIdx.x * 4 + wave) * RPW_F;

    __shared__ float4 part[256];

    if (blockIdx.x < 64) {                       // phase 1: csum
        const int t = threadIdx.x;
        const int c = t & 7;
        const int g = t >> 3;
        const int col4 = blockIdx.x * 8 + c;
        const float4* p = (const float4*)coeffs + (size_t)(g * 4) * F4 + col4;
        float4 s = make_float4(0.f, 0.f, 0.f, 0.f);
#pragma unroll
        for (int n = 0; n < 4; ++n) {
            float4 v = p[(size_t)n * F4];
            s.x += v.x; s.y += v.y; s.z += v.z; s.w += v.w;
        }
        part[t] = s;
        __syncthreads();
#pragma unroll
        for (int stride = 128; stride >= 8; stride >>= 1) {
            if (t < stride) {
                float4 o = part[t + stride];
                float4 m = part[t];
                m.x += o.x; m.y += o.y; m.z += o.z; m.w += o.w;
                part[t] = m;
            }
            __syncthreads();
        }
        if (t < 8) ((float4*)csum)[blockIdx.x * 8 + t] = part[t];
        __threadfence();
    }

    // preload x (independent of csum; hides phase 1 + sync under the drain)
    float4 xv[RPW_F];
    const float4* xr = (const float4*)x + (size_t)row0 * XR4 + lane;
#pragma unroll
    for (int r = 0; r < RPW_F; ++r) xv[r] = xr[(size_t)r * XR4];

    grid.sync();

    float c[4][8];
    const float4* c4 = (const float4*)csum + (size_t)lane * 8;
#pragma unroll
    for (int j = 0; j < 4; ++j) {
        float4 a = c4[j * 2];
        float4 b = c4[j * 2 + 1];
        c[j][0] = a.x; c[j][1] = a.y; c[j][2] = a.z; c[j][3] = a.w;
        c[j][4] = b.x; c[j][5] = b.y; c[j][6] = b.z; c[j][7] = b.w;
    }

    float acc[RPW_F];
#pragma unroll
    for (int r = 0; r < RPW_F; ++r) {
        float xs[4] = {xv[r].x, xv[r].y, xv[r].z, xv[r].w};
        float a = 0.f;
#pragma unroll
        for (int j = 0; j < 4; ++j) {
            const float xx = xs[j];
            const float two_x = xx + xx;
            a = fmaf(c[j][1], xx, a + c[j][0]);
            float tp = 1.f, tc = xx;
#pragma unroll
            for (int d = 2; d < 8; ++d) {
                float tn = fmaf(two_x, tc, -tp);
                a = fmaf(c[j][d], tn, a);
                tp = tc; tc = tn;
            }
        }
        acc[r] = a;
    }

#pragma unroll
    for (int rq = 0; rq < RPW_F / 4; ++rq) {
        float s[4];
#pragma unroll
        for (int k = 0; k < 4; ++k) {
            float a = acc[rq * 4 + k];
#pragma unroll
            for (int off = 32; off > 0; off >>= 1) a += __shfl_down(a, off, 64);
            s[k] = a;
        }
        if (lane == 0)
            ((float4*)out)[row0 / 4 + rq] = make_float4(s[0], s[1], s[2], s[3]);
    }
}

extern "C" void kernel_launch(void* const* d_in, const int* in_sizes, int n_in,
                              void* d_out, int out_size, void* d_ws, size_t ws_size,
                              hipStream_t stream) {
    const float* x      = (const float*)d_in[0];   // [32768, 256]
    const float* coeffs = (const float*)d_in[1];   // [128, 2048]
    float* out  = (float*)d_out;                   // [32768, 1]
    float* csum = (float*)d_ws;                    // 2048 floats scratch

    void* args[] = {(void*)&x, (void*)&coeffs, (void*)&out, (void*)&csum};
    hipError_t err = hipLaunchCooperativeKernel((const void*)kan_fused,
                                                dim3(NBLK_F), dim3(256),
                                                args, 0, stream);
    if (err != hipSuccess) {
        // Deterministic fallback (same every call): proven two-kernel path.
        reduce_coeffs<<<64, 256, 0, stream>>>(coeffs, csum);
        kan_fwd<<<BATCH / (4 * RPW), 256, 0, stream>>>(x, csum, out);
    }
}

// Round 5
// 77.389 us; speedup vs baseline: 2.3496x; 2.3496x over previous
//
#include <hip/hip_runtime.h>

#define BATCH     32768
#define IN_DIM    256
#define N_NEURONS 128
#define DEG1      8                    // MAX_DEGREE+1
#define FEAT      (IN_DIM * DEG1)      // 2048
#define F4        (FEAT / 4)           // 512 float4 columns
#define XR4       (IN_DIM / 4)         // 64 float4 per x row
#define RPW       16                   // rows per wave

// ---------------------------------------------------------------------------
// out[b] = sum_f X[b,f]*csum[f] with csum[f] = sum_n coeffs[n,f]  — the
// neuron sum commutes with the feature dot product, collapsing the
// [32768x2048]x[2048x128] GEMM to a 2048-wide weighted Chebyshev eval.
// Memory floor: 32 MiB x-read ≈ 5.3 µs @6.3 TB/s; coeffs 1 MiB; out 128 KiB.
//
// NOTE (round 3/4): cooperative-kernel fusion was tried and abandoned —
// cg::grid.sync() on gfx950 costs ~100 µs at 1024 blocks (VALUBusy 2.3%),
// 30x the two-launch serialization it would remove.
// ---------------------------------------------------------------------------

// Kernel 1: csum[f] = sum_n coeffs[n, f]. 64 blocks x 256 threads; thread
// (g,c) sums 4 neurons of float4-column c; LDS tree over the 32 groups.
__global__ __launch_bounds__(256) void reduce_coeffs(const float* __restrict__ coeffs,
                                                     float* __restrict__ csum) {
    __shared__ float4 part[256];
    const int t = threadIdx.x;
    const int c = t & 7;                     // float4-col within block
    const int g = t >> 3;                    // neuron group of 4
    const int col4 = blockIdx.x * 8 + c;     // 64 * 8 = 512 float4 columns

    const float4* p = (const float4*)coeffs + (size_t)(g * 4) * F4 + col4;
    float4 s = make_float4(0.f, 0.f, 0.f, 0.f);
#pragma unroll
    for (int n = 0; n < 4; ++n) {
        float4 v = p[(size_t)n * F4];
        s.x += v.x; s.y += v.y; s.z += v.z; s.w += v.w;
    }
    part[t] = s;
    __syncthreads();
#pragma unroll
    for (int stride = 128; stride >= 8; stride >>= 1) {
        if (t < stride) {
            float4 o = part[t + stride];
            float4 m = part[t];
            m.x += o.x; m.y += o.y; m.z += o.z; m.w += o.w;
            part[t] = m;
        }
        __syncthreads();
    }
    if (t < 8) ((float4*)csum)[blockIdx.x * 8 + t] = part[t];
}

// Kernel 2: one wave per 16 rows; lane l owns dims 4l..4l+3 (one coalesced
// float4 x-load per row per lane). Per-lane coefficients (32 floats) in
// registers amortized over 16 rows; wave shuffle-reduce; float4 stores.
__global__ __launch_bounds__(256) void kan_fwd(const float* __restrict__ x,
                                               const float* __restrict__ csum,
                                               float* __restrict__ out) {
    const int lane = threadIdx.x & 63;
    const int wave = threadIdx.x >> 6;                   // 0..3
    const int row0 = (blockIdx.x * 4 + wave) * RPW;      // 512 blocks

    float c[4][8];
    const float4* c4 = (const float4*)csum + (size_t)lane * 8;
#pragma unroll
    for (int j = 0; j < 4; ++j) {
        float4 a = c4[j * 2];
        float4 b = c4[j * 2 + 1];
        c[j][0] = a.x; c[j][1] = a.y; c[j][2] = a.z; c[j][3] = a.w;
        c[j][4] = b.x; c[j][5] = b.y; c[j][6] = b.z; c[j][7] = b.w;
    }

    float acc[RPW];
    const float4* xr = (const float4*)x + (size_t)row0 * XR4 + lane;
#pragma unroll
    for (int r = 0; r < RPW; ++r) {
        float4 xv = xr[(size_t)r * XR4];
        float xs[4] = {xv.x, xv.y, xv.z, xv.w};
        float a = 0.f;
#pragma unroll
        for (int j = 0; j < 4; ++j) {
            const float xx = xs[j];
            const float two_x = xx + xx;
            a = fmaf(c[j][1], xx, a + c[j][0]);   // T0=1, T1=x
            float tp = 1.f, tc = xx;
#pragma unroll
            for (int d = 2; d < 8; ++d) {
                float tn = fmaf(two_x, tc, -tp);  // T_d = 2x*T_{d-1} - T_{d-2}
                a = fmaf(c[j][d], tn, a);
                tp = tc; tc = tn;
            }
        }
        acc[r] = a;
    }

#pragma unroll
    for (int rq = 0; rq < RPW / 4; ++rq) {
        float s[4];
#pragma unroll
        for (int k = 0; k < 4; ++k) {
            float a = acc[rq * 4 + k];
#pragma unroll
            for (int off = 32; off > 0; off >>= 1) a += __shfl_down(a, off, 64);
            s[k] = a;
        }
        if (lane == 0)
            ((float4*)out)[row0 / 4 + rq] = make_float4(s[0], s[1], s[2], s[3]);
    }
}

extern "C" void kernel_launch(void* const* d_in, const int* in_sizes, int n_in,
                              void* d_out, int out_size, void* d_ws, size_t ws_size,
                              hipStream_t stream) {
    const float* x      = (const float*)d_in[0];   // [32768, 256]
    const float* coeffs = (const float*)d_in[1];   // [128, 2048]
    float* out  = (float*)d_out;                   // [32768, 1]
    float* csum = (float*)d_ws;                    // 2048 floats scratch

    reduce_coeffs<<<64, 256, 0, stream>>>(coeffs, csum);
    kan_fwd<<<BATCH / (4 * RPW), 256, 0, stream>>>(x, csum, out);
}